// Round 5
// baseline (241.032 us; speedup 1.0000x reference)
//
#include <hip/hip_runtime.h>
#include <hip/hip_bf16.h>

typedef __bf16 bf16x8 __attribute__((ext_vector_type(8)));
typedef __attribute__((ext_vector_type(4))) float floatx4;

#define BATCH 512
#define S1 10
#define S2 25
#define NK1 (BATCH * S1)    // 5120
#define NK2 (NK1 * S2)      // 128000
#define MROWS (BATCH + NK1) // 5632

__device__ __forceinline__ ushort f2b(float x) {
    unsigned u = __builtin_bit_cast(unsigned, x);
    u += 0x7fffu + ((u >> 16) & 1u);   // RNE
    return (ushort)(u >> 16);
}
__device__ __forceinline__ float b2f(ushort b) {
    unsigned u = ((unsigned)b) << 16;
    return __builtin_bit_cast(float, u);
}

// K1: blocks [0,512): neighbor sampling (n1 then n2, same block -> no cross-block dep)
//     blocks [512,896): pack 4 weight mats f32 -> bf16 in MFMA-B-fragment order
//     packed layout: wpack[((nt*KS + ks)*64 + lane)*8 + j] = W[(ks*32 + 8*(lane>>4) + j)*128 + nt*16 + (lane&15)]
__global__ void k_sample_pack(const int* __restrict__ adj,
                              const int* __restrict__ batch1,
                              const int* __restrict__ cols1,
                              const int* __restrict__ cols2,
                              const float* __restrict__ ws0, const float* __restrict__ wn0,
                              const float* __restrict__ ws1, const float* __restrict__ wn1,
                              int* __restrict__ n1, int* __restrict__ n2,
                              ushort* __restrict__ wpack) {
    __shared__ int sn1[S1];
    int bid = blockIdx.x, tid = threadIdx.x;
    if (bid < BATCH) {
        int bnode = batch1[bid];
        if (tid < S1) {
            int c = cols1[bid * S1 + tid];
            int v = adj[bnode * 128 + c];
            sn1[tid] = v;
            n1[bid * S1 + tid] = v;
        }
        __syncthreads();
        if (tid < S1 * S2) {
            int j = tid / S2, l = tid - j * S2;
            int k = bid * S1 + j;
            int c = cols2[k * S2 + l];
            n2[k * S2 + l] = adj[sn1[j] * 128 + c];
        }
    } else {
        int pg = (bid - BATCH) * 256 + tid;   // [0, 98304)
        const float* src; int KS; int p;
        if (pg < 16384)      { src = ws0; KS = 4; p = pg; }
        else if (pg < 32768) { src = wn0; KS = 4; p = pg - 16384; }
        else if (pg < 65536) { src = ws1; KS = 8; p = pg - 32768; }
        else                 { src = wn1; KS = 8; p = pg - 65536; }
        int j = p & 7, l = (p >> 3) & 63, rest = p >> 9;
        int ks = rest % KS, nt = rest / KS;
        int k = ks * 32 + 8 * (l >> 4) + j;
        int n = nt * 16 + (l & 15);
        wpack[pg] = f2b(src[k * 128 + n]);
    }
}

// K2: one wave per row. blocks [0,5120): n1 rows (self=features[n1], neigh=mean25 of n2)
//     blocks [5120,5632): batch rows (self=features[batch], neigh=mean10 of n1)
//     xs/xn rows: 0..511 = batch rows, 512..5631 = n1 rows (matches H layout for layer 1)
__global__ void k_gather(const float* __restrict__ feat,
                         const int* __restrict__ batch1,
                         const int* __restrict__ n1, const int* __restrict__ n2,
                         ushort* __restrict__ xs, ushort* __restrict__ xn) {
    int k = blockIdx.x, t = threadIdx.x;   // 64 threads, float2 per lane
    const float2* f2 = (const float2*)feat;
    int row, selfidx; const int* nn; int cnt; float inv;
    if (k < NK1) { row = BATCH + k; selfidx = n1[k]; nn = n2 + k * S2; cnt = S2; inv = 1.f / S2; }
    else { int i = k - NK1; row = i; selfidx = batch1[i]; nn = n1 + i * S1; cnt = S1; inv = 1.f / S1; }
    float2 h = f2[(long long)selfidx * 64 + t];
    ((unsigned*)xs)[row * 64 + t] = (unsigned)f2b(h.x) | ((unsigned)f2b(h.y) << 16);
    float sx = 0.f, sy = 0.f;
    for (int l = 0; l < cnt; l++) {
        float2 v = f2[(long long)nn[l] * 64 + t];
        sx += v.x; sy += v.y;
    }
    ((unsigned*)xn)[row * 64 + t] = (unsigned)f2b(sx * inv) | ((unsigned)f2b(sy * inv) << 16);
}

// K3: layer-0 GEMM. H[5632,256] = relu([xs@Ws0 | xn@Wn0]), bf16 out. 64-row tiles, 4 waves.
__global__ __launch_bounds__(256) void k_gemm0(const ushort* __restrict__ xs,
                                               const ushort* __restrict__ xn,
                                               const ushort* __restrict__ wpack,
                                               ushort* __restrict__ H) {
    __shared__ __align__(16) ushort A2[2][64][136];   // +8 bf16 pad: row pitch 272B -> <=2-way bank conflict
    int r0 = blockIdx.x * 64;
    int tid = threadIdx.x;
    for (int idx = tid; idx < 2048; idx += 256) {
        int buf = idx >> 10, row = (idx >> 4) & 63, seg = idx & 15;
        const uint4* src = (const uint4*)(buf ? xn : xs);
        uint4 v = src[(r0 + row) * 16 + seg];
        *(uint4*)&A2[buf][row][seg * 8] = v;
    }
    __syncthreads();
    int wave = tid >> 6, lane = tid & 63;
    int arow = wave * 16 + (lane & 15);
    int acol = 8 * (lane >> 4);
    bf16x8 afrag[2][4];
#pragma unroll
    for (int h = 0; h < 2; h++)
#pragma unroll
        for (int ks = 0; ks < 4; ks++)
            afrag[h][ks] = *(const bf16x8*)&A2[h][arow][ks * 32 + acol];
    int orow = r0 + wave * 16 + (lane >> 4) * 4;
    int ocol = lane & 15;
#pragma unroll
    for (int h = 0; h < 2; h++) {
        const bf16x8* wp = (const bf16x8*)(wpack + h * 16384);
#pragma unroll
        for (int nt = 0; nt < 8; nt++) {
            floatx4 acc = {0.f, 0.f, 0.f, 0.f};
#pragma unroll
            for (int ks = 0; ks < 4; ks++)
                acc = __builtin_amdgcn_mfma_f32_16x16x32_bf16(afrag[h][ks], wp[(nt * 4 + ks) * 64 + lane], acc, 0, 0, 0);
#pragma unroll
            for (int q = 0; q < 4; q++) {
                float v = acc[q] > 0.f ? acc[q] : 0.f;   // relu (layer 0)
                H[(orow + q) * 256 + h * 128 + nt * 16 + ocol] = f2b(v);
            }
        }
    }
}

// K4: layer-1. out[512,256] = [H0@Ws1 | mean10(H1)@Wn1], f32 out, no act. 32-row tiles, 2 waves.
__global__ __launch_bounds__(128) void k_gemm1(const ushort* __restrict__ H,
                                               const ushort* __restrict__ wpack,
                                               float* __restrict__ out) {
    __shared__ __align__(16) ushort A2[2][32][264];
    int i0 = blockIdx.x * 32;
    int tid = threadIdx.x;
    const uint4* H4 = (const uint4*)H;   // 32 uint4 per 256-col bf16 row
    for (int idx = tid; idx < 1024; idx += 128) {    // self rows
        int row = idx >> 5, seg = idx & 31;
        uint4 v = H4[(i0 + row) * 32 + seg];
        *(uint4*)&A2[0][row][seg * 8] = v;
    }
    for (int idx = tid; idx < 1024; idx += 128) {    // neighbor means (f32 accum)
        int row = idx >> 5, seg = idx & 31;
        float s[8] = {0, 0, 0, 0, 0, 0, 0, 0};
        int base = BATCH + (i0 + row) * S1;
        for (int j = 0; j < S1; j++) {
            uint4 v = H4[(base + j) * 32 + seg];
            unsigned u[4] = {v.x, v.y, v.z, v.w};
#pragma unroll
            for (int q = 0; q < 4; q++) {
                s[q * 2]     += b2f((ushort)(u[q] & 0xffffu));
                s[q * 2 + 1] += b2f((ushort)(u[q] >> 16));
            }
        }
        unsigned o[4];
#pragma unroll
        for (int q = 0; q < 4; q++)
            o[q] = (unsigned)f2b(s[q * 2] * 0.1f) | ((unsigned)f2b(s[q * 2 + 1] * 0.1f) << 16);
        uint4 ov = make_uint4(o[0], o[1], o[2], o[3]);
        *(uint4*)&A2[1][row][seg * 8] = ov;
    }
    __syncthreads();
    int wave = tid >> 6, lane = tid & 63;
    int arow = wave * 16 + (lane & 15);
    int acol = 8 * (lane >> 4);
    int orow = i0 + wave * 16 + (lane >> 4) * 4;
    int ocol = lane & 15;
#pragma unroll
    for (int h = 0; h < 2; h++) {
        bf16x8 a[8];
#pragma unroll
        for (int ks = 0; ks < 8; ks++)
            a[ks] = *(const bf16x8*)&A2[h][arow][ks * 32 + acol];
        const bf16x8* wp = (const bf16x8*)(wpack + 32768 + h * 32768);
#pragma unroll
        for (int nt = 0; nt < 8; nt++) {
            floatx4 acc = {0.f, 0.f, 0.f, 0.f};
#pragma unroll
            for (int ks = 0; ks < 8; ks++)
                acc = __builtin_amdgcn_mfma_f32_16x16x32_bf16(a[ks], wp[(nt * 8 + ks) * 64 + lane], acc, 0, 0, 0);
#pragma unroll
            for (int q = 0; q < 4; q++)
                out[(orow + q) * 256 + h * 128 + nt * 16 + ocol] = acc[q];
        }
    }
}

extern "C" void kernel_launch(void* const* d_in, const int* in_sizes, int n_in,
                              void* d_out, int out_size, void* d_ws, size_t ws_size,
                              hipStream_t stream) {
    const float* features = (const float*)d_in[0];
    const int*   adj      = (const int*)d_in[1];   // integer inputs are staged as int32
    const int*   batch1   = (const int*)d_in[2];
    const int*   cols1    = (const int*)d_in[3];
    const int*   cols2    = (const int*)d_in[4];
    const float* ws0      = (const float*)d_in[5];
    const float* wn0      = (const float*)d_in[6];
    const float* ws1      = (const float*)d_in[7];
    const float* wn1      = (const float*)d_in[8];
    float* out = (float*)d_out;

    char* p = (char*)d_ws;
    int*    n1    = (int*)p;                    // 20480 B
    int*    n2    = (int*)(p + 20480);          // 512000 B -> 532480
    ushort* xs    = (ushort*)(p + 532480);      // 5632*128 bf16 -> 1974272
    ushort* xn    = (ushort*)(p + 1974272);     // -> 3416064
    ushort* H     = (ushort*)(p + 3416064);     // 5632*256 bf16 -> 6299648
    ushort* wpack = (ushort*)(p + 6299648);     // 98304 bf16 -> 6496256 total

    if (ws_size < (size_t)6496256) return;      // diagnostic guard: fail clean, not a fault

    hipLaunchKernelGGL(k_sample_pack, dim3(896), dim3(256), 0, stream,
                       adj, batch1, cols1, cols2, ws0, wn0, ws1, wn1, n1, n2, wpack);
    hipLaunchKernelGGL(k_gather, dim3(MROWS), dim3(64), 0, stream,
                       features, batch1, n1, n2, xs, xn);
    hipLaunchKernelGGL(k_gemm0, dim3(MROWS / 64), dim3(256), 0, stream,
                       xs, xn, wpack, H);
    hipLaunchKernelGGL(k_gemm1, dim3(BATCH / 32), dim3(128), 0, stream,
                       H, wpack, out);
}

// Round 9
// 227.784 us; speedup vs baseline: 1.0582x; 1.0582x over previous
//
#include <hip/hip_runtime.h>
#include <hip/hip_bf16.h>

typedef __bf16 bf16x8 __attribute__((ext_vector_type(8)));
typedef __attribute__((ext_vector_type(4))) float floatx4;

#define BATCH 512
#define S1 10
#define S2 25

__device__ __forceinline__ ushort f2b(float x) {
    unsigned u = __builtin_bit_cast(unsigned, x);
    u += 0x7fffu + ((u >> 16) & 1u);   // RNE
    return (ushort)(u >> 16);
}
__device__ __forceinline__ float b2f(ushort b) {
    unsigned u = ((unsigned)b) << 16;
    return __builtin_bit_cast(float, u);
}
__device__ __forceinline__ unsigned pk2(float a, float b) {
    return (unsigned)f2b(a) | ((unsigned)f2b(b) << 16);
}

// K_pack: pack 4 weight mats f32 -> bf16 in MFMA-B-fragment order. 384 blocks x 256.
// wpack[((nt*KS + ks)*64 + lane)*8 + j] = W[(ks*32 + 8*(lane>>4) + j)*128 + nt*16 + (lane&15)]
// regions (elements): ws0 @0, wn0 @16384, ws1 @32768, wn1 @65536  (total 98304)
__global__ void k_pack(const float* __restrict__ ws0, const float* __restrict__ wn0,
                       const float* __restrict__ ws1, const float* __restrict__ wn1,
                       ushort* __restrict__ wpack) {
    int pg = blockIdx.x * 256 + threadIdx.x;   // [0, 98304)
    const float* src; int KS; int p;
    if (pg < 16384)      { src = ws0; KS = 4; p = pg; }
    else if (pg < 32768) { src = wn0; KS = 4; p = pg - 16384; }
    else if (pg < 65536) { src = ws1; KS = 8; p = pg - 32768; }
    else                 { src = wn1; KS = 8; p = pg - 65536; }
    int j = p & 7, l = (p >> 3) & 63, rest = p >> 9;
    int ks = rest % KS, nt = rest / KS;
    int k = ks * 32 + 8 * (l >> 4) + j;
    int n = nt * 16 + (l & 15);
    wpack[pg] = f2b(src[k * 128 + n]);
}

// K_fused: one block per batch element. sample -> gather+mean -> L0 GEMM -> mean10 -> L1 GEMM -> out.
__global__ __launch_bounds__(256) void k_fused(const float* __restrict__ feat,
                                               const int* __restrict__ adj,
                                               const int* __restrict__ batch1,
                                               const int* __restrict__ cols1,
                                               const int* __restrict__ cols2,
                                               const ushort* __restrict__ wpack,
                                               float* __restrict__ out) {
    __shared__ int sn1[S1];
    __shared__ int sn2[S1 * S2];
    __shared__ __align__(16) ushort xs[16][136];   // L0 A-tile (self), rows 0..10 valid; pitch 272B
    __shared__ __align__(16) ushort xn[16][136];   // L0 A-tile (neigh means)
    __shared__ __align__(16) ushort Hl[16][264];   // L0 output (relu, bf16); row 11 reused for mean10

    int b = blockIdx.x, tid = threadIdx.x;
    int wave = tid >> 6, lane = tid & 63;

    // ---- phase 1: neighbor sampling (block-local hierarchy) ----
    if (tid < S1) {
        int c = cols1[b * S1 + tid];
        sn1[tid] = adj[batch1[b] * 128 + c];
    }
    __syncthreads();
    if (tid < S1 * S2) {
        int j = tid / S2, l = tid - j * S2;
        sn2[tid] = adj[sn1[j] * 128 + cols2[(b * S1 + j) * S2 + l]];
    }
    __syncthreads();

    // ---- phase 2: feature gather + means -> xs/xn rows 0..10 (bf16) ----
    // row 0: self=feat[batch1[b]], neigh=mean10(feat[sn1[*]])
    // row 1+j: self=feat[sn1[j]], neigh=mean25(feat[sn2[j][*]])
    {
        const float2* f2p = (const float2*)feat;
        for (int g = wave; g < 11; g += 4) {
            int selfidx; const int* lst; int cnt; float inv;
            if (g == 0) { selfidx = batch1[b]; lst = sn1; cnt = S1; inv = 1.f / S1; }
            else        { selfidx = sn1[g - 1]; lst = sn2 + (g - 1) * S2; cnt = S2; inv = 1.f / S2; }
            float2 h = f2p[(long long)selfidx * 64 + lane];
            ((unsigned*)&xs[g][0])[lane] = pk2(h.x, h.y);
            float sx = 0.f, sy = 0.f;
            for (int l = 0; l < cnt; l++) {
                float2 v = f2p[(long long)lst[l] * 64 + lane];
                sx += v.x; sy += v.y;
            }
            ((unsigned*)&xn[g][0])[lane] = pk2(sx * inv, sy * inv);
        }
    }
    __syncthreads();

    // ---- phase 2b: layer-0 GEMM (M-tile=16, rows 0..10 valid) -> Hl rows, relu, bf16 ----
    // 16 global nt: 0..7 = xs@Ws0 (H cols 0..127), 8..15 = xn@Wn0 (H cols 128..255). 4 nt/wave.
    {
        int ntg0 = wave * 4;
        const ushort (*At)[136] = (ntg0 < 8) ? xs : xn;
        int arow = lane & 15, acol = 8 * (lane >> 4);
        bf16x8 af[4];
#pragma unroll
        for (int ks = 0; ks < 4; ks++)
            af[ks] = *(const bf16x8*)&At[arow][ks * 32 + acol];
#pragma unroll
        for (int t = 0; t < 4; t++) {
            int ntg = ntg0 + t;
            int half = ntg >> 3, ntl = ntg & 7;
            const bf16x8* wp = (const bf16x8*)(wpack + half * 16384);
            floatx4 acc = {0.f, 0.f, 0.f, 0.f};
#pragma unroll
            for (int ks = 0; ks < 4; ks++)
                acc = __builtin_amdgcn_mfma_f32_16x16x32_bf16(af[ks], wp[(ntl * 4 + ks) * 64 + lane], acc, 0, 0, 0);
            int col = half * 128 + ntl * 16 + (lane & 15);
#pragma unroll
            for (int q = 0; q < 4; q++) {
                float v = acc[q] > 0.f ? acc[q] : 0.f;   // relu (layer 0)
                Hl[(lane >> 4) * 4 + q][col] = f2b(v);
            }
        }
    }
    __syncthreads();

    // ---- phase 3: mean10 of Hl rows 1..10 -> Hl row 11 (bf16, f32 accum) ----
    {
        float s = 0.f;
#pragma unroll
        for (int j = 1; j <= S1; j++) s += b2f(Hl[j][tid]);
        Hl[11][tid] = f2b(s * (1.f / S1));
    }
    __syncthreads();

    // ---- phase 4: layer-1 GEMMs via broadcast-row A-frag (all lanes read same Hl row) ----
    // D[r][c] = A[r]·B[c]; all A rows identical -> every D row is the answer; use lanes 0..15, q=0.
    // 16 nt: 0..7 = Hl[0]@Ws1 (out cols 0..127), 8..15 = Hl[11]@Wn1 (out cols 128..255).
    {
        int ntg0 = wave * 4;
#pragma unroll
        for (int t = 0; t < 4; t++) {
            int ntg = ntg0 + t;
            int half = ntg >> 3, ntl = ntg & 7;
            int srcrow = half ? 11 : 0;
            const bf16x8* wp = (const bf16x8*)(wpack + 32768 + half * 32768);
            floatx4 acc = {0.f, 0.f, 0.f, 0.f};
#pragma unroll
            for (int ks = 0; ks < 8; ks++) {
                bf16x8 a = *(const bf16x8*)&Hl[srcrow][ks * 32 + 8 * (lane >> 4)];
                acc = __builtin_amdgcn_mfma_f32_16x16x32_bf16(a, wp[(ntl * 8 + ks) * 64 + lane], acc, 0, 0, 0);
            }
            if (lane < 16)
                out[b * 256 + half * 128 + ntl * 16 + lane] = acc[0];
        }
    }
}

extern "C" void kernel_launch(void* const* d_in, const int* in_sizes, int n_in,
                              void* d_out, int out_size, void* d_ws, size_t ws_size,
                              hipStream_t stream) {
    const float* features = (const float*)d_in[0];
    const int*   adj      = (const int*)d_in[1];   // integer inputs staged as int32
    const int*   batch1   = (const int*)d_in[2];
    const int*   cols1    = (const int*)d_in[3];
    const int*   cols2    = (const int*)d_in[4];
    const float* ws0      = (const float*)d_in[5];
    const float* wn0      = (const float*)d_in[6];
    const float* ws1      = (const float*)d_in[7];
    const float* wn1      = (const float*)d_in[8];
    float* out = (float*)d_out;

    ushort* wpack = (ushort*)d_ws;                 // 98304 bf16 = 196608 B
    if (ws_size < (size_t)196608) return;          // diagnostic guard

    hipLaunchKernelGGL(k_pack, dim3(384), dim3(256), 0, stream, ws0, wn0, ws1, wn1, wpack);
    hipLaunchKernelGGL(k_fused, dim3(BATCH), dim3(256), 0, stream,
                       features, adj, batch1, cols1, cols2, wpack, out);
}

// Round 10
// 199.681 us; speedup vs baseline: 1.2071x; 1.1407x over previous
//
#include <hip/hip_runtime.h>
#include <hip/hip_bf16.h>

typedef __bf16 bf16x8 __attribute__((ext_vector_type(8)));
typedef __attribute__((ext_vector_type(4))) float floatx4;

#define BATCH 512
#define S1 10
#define S2 25

__device__ __forceinline__ ushort f2b(float x) {
    unsigned u = __builtin_bit_cast(unsigned, x);
    u += 0x7fffu + ((u >> 16) & 1u);   // RNE
    return (ushort)(u >> 16);
}
__device__ __forceinline__ float b2f(ushort b) {
    unsigned u = ((unsigned)b) << 16;
    return __builtin_bit_cast(float, u);
}
__device__ __forceinline__ unsigned pk2(float a, float b) {
    return (unsigned)f2b(a) | ((unsigned)f2b(b) << 16);
}

// K_pack: pack 4 weight mats f32 -> bf16 in MFMA-B-fragment order. 384 blocks x 256.
// wpack[((nt*KS + ks)*64 + lane)*8 + j] = W[(ks*32 + 8*(lane>>4) + j)*128 + nt*16 + (lane&15)]
// regions (elements): ws0 @0, wn0 @16384, ws1 @32768, wn1 @65536  (total 98304)
__global__ void k_pack(const float* __restrict__ ws0, const float* __restrict__ wn0,
                       const float* __restrict__ ws1, const float* __restrict__ wn1,
                       ushort* __restrict__ wpack) {
    int pg = blockIdx.x * 256 + threadIdx.x;   // [0, 98304)
    const float* src; int KS; int p;
    if (pg < 16384)      { src = ws0; KS = 4; p = pg; }
    else if (pg < 32768) { src = wn0; KS = 4; p = pg - 16384; }
    else if (pg < 65536) { src = ws1; KS = 8; p = pg - 32768; }
    else                 { src = wn1; KS = 8; p = pg - 65536; }
    int j = p & 7, l = (p >> 3) & 63, rest = p >> 9;
    int ks = rest % KS, nt = rest / KS;
    int k = ks * 32 + 8 * (l >> 4) + j;
    int n = nt * 16 + (l & 15);
    wpack[pg] = f2b(src[k * 128 + n]);
}

// K_fused: one block (512 thr, 8 waves) per batch element.
// sample -> gather+mean (unrolled, deep MLP) -> L0 GEMM -> mean10 -> L1 GEMM -> out.
__global__ __launch_bounds__(512, 4) void k_fused(const float* __restrict__ feat,
                                                  const int* __restrict__ adj,
                                                  const int* __restrict__ batch1,
                                                  const int* __restrict__ cols1,
                                                  const int* __restrict__ cols2,
                                                  const ushort* __restrict__ wpack,
                                                  float* __restrict__ out) {
    __shared__ int sn1[S1];
    __shared__ int sn2[S1 * S2];
    __shared__ __align__(16) ushort xs[16][136];   // L0 A-tile (self), rows 0..10 valid; pitch 272B
    __shared__ __align__(16) ushort xn[16][136];   // L0 A-tile (neigh means)
    __shared__ __align__(16) ushort Hl[16][264];   // L0 output (relu, bf16); row 11 = mean10

    int b = blockIdx.x, tid = threadIdx.x;
    int wave = tid >> 6, lane = tid & 63;

    // ---- phase 1: neighbor sampling (block-local hierarchy) ----
    if (tid < S1) {
        int c = cols1[b * S1 + tid];
        sn1[tid] = adj[batch1[b] * 128 + c];
    }
    __syncthreads();
    if (tid < S1 * S2) {
        int j = tid / S2, l = tid - j * S2;
        sn2[tid] = adj[sn1[j] * 128 + cols2[(b * S1 + j) * S2 + l]];
    }
    __syncthreads();

    // ---- phase 2: feature gather + means -> xs/xn rows 0..10 (bf16) ----
    // row 0: self=feat[batch1[b]], neigh=mean10(feat[sn1[*]])
    // row 1+j: self=feat[sn1[j]], neigh=mean25(feat[sn2[j][*]])
    // Compile-time trip counts + unroll -> ~25 loads in flight per wave.
    {
        const float2* f2p = (const float2*)feat;
        for (int g = wave; g < 11; g += 8) {
            int selfidx = (g == 0) ? batch1[b] : sn1[g - 1];
            float2 h = f2p[(long long)selfidx * 64 + lane];
            ((unsigned*)&xs[g][0])[lane] = pk2(h.x, h.y);
            float sx = 0.f, sy = 0.f;
            if (g == 0) {
#pragma unroll
                for (int l = 0; l < S1; l++) {
                    float2 v = f2p[(long long)sn1[l] * 64 + lane];
                    sx += v.x; sy += v.y;
                }
                sx *= (1.f / S1); sy *= (1.f / S1);
            } else {
                const int* lst = sn2 + (g - 1) * S2;
#pragma unroll
                for (int l = 0; l < S2; l++) {
                    float2 v = f2p[(long long)lst[l] * 64 + lane];
                    sx += v.x; sy += v.y;
                }
                sx *= (1.f / S2); sy *= (1.f / S2);
            }
            ((unsigned*)&xn[g][0])[lane] = pk2(sx, sy);
        }
    }
    __syncthreads();

    // ---- phase 2b: layer-0 GEMM (M-tile=16, rows 0..10 valid) -> Hl rows, relu, bf16 ----
    // 16 global nt over 8 waves (2 each): waves 0-3 = xs@Ws0 (cols 0..127), 4-7 = xn@Wn0 (128..255).
    {
        const ushort (*At)[136] = (wave < 4) ? xs : xn;
        int arow = lane & 15, acol = 8 * (lane >> 4);
        bf16x8 af[4];
#pragma unroll
        for (int ks = 0; ks < 4; ks++)
            af[ks] = *(const bf16x8*)&At[arow][ks * 32 + acol];
        int ntg0 = wave * 2;
#pragma unroll
        for (int t = 0; t < 2; t++) {
            int ntg = ntg0 + t;
            int half = ntg >> 3, ntl = ntg & 7;
            const bf16x8* wp = (const bf16x8*)(wpack + half * 16384);
            floatx4 acc = {0.f, 0.f, 0.f, 0.f};
#pragma unroll
            for (int ks = 0; ks < 4; ks++)
                acc = __builtin_amdgcn_mfma_f32_16x16x32_bf16(af[ks], wp[(ntl * 4 + ks) * 64 + lane], acc, 0, 0, 0);
            int col = half * 128 + ntl * 16 + (lane & 15);
#pragma unroll
            for (int q = 0; q < 4; q++) {
                float v = acc[q] > 0.f ? acc[q] : 0.f;   // relu (layer 0)
                Hl[(lane >> 4) * 4 + q][col] = f2b(v);
            }
        }
    }
    __syncthreads();

    // ---- phase 3: mean10 of Hl rows 1..10 -> Hl row 11 (bf16, f32 accum) ----
    if (tid < 256) {
        float s = 0.f;
#pragma unroll
        for (int j = 1; j <= S1; j++) s += b2f(Hl[j][tid]);
        Hl[11][tid] = f2b(s * (1.f / S1));
    }
    __syncthreads();

    // ---- phase 4: layer-1 GEMMs via broadcast-row A-frag (all lanes read same Hl row) ----
    // D[r][c] = A[r]·B[c]; all A rows identical -> D row 0 is the answer; lanes 0..15, q=0.
    // 16 nt over 8 waves: 0..7 = Hl[0]@Ws1 (out cols 0..127), 8..15 = Hl[11]@Wn1 (128..255).
    {
        int ntg0 = wave * 2;
#pragma unroll
        for (int t = 0; t < 2; t++) {
            int ntg = ntg0 + t;
            int half = ntg >> 3, ntl = ntg & 7;
            int srcrow = half ? 11 : 0;
            const bf16x8* wp = (const bf16x8*)(wpack + 32768 + half * 32768);
            floatx4 acc = {0.f, 0.f, 0.f, 0.f};
#pragma unroll
            for (int ks = 0; ks < 8; ks++) {
                bf16x8 a = *(const bf16x8*)&Hl[srcrow][ks * 32 + 8 * (lane >> 4)];
                acc = __builtin_amdgcn_mfma_f32_16x16x32_bf16(a, wp[(ntl * 8 + ks) * 64 + lane], acc, 0, 0, 0);
            }
            if (lane < 16)
                out[b * 256 + half * 128 + ntl * 16 + lane] = acc[0];
        }
    }
}

extern "C" void kernel_launch(void* const* d_in, const int* in_sizes, int n_in,
                              void* d_out, int out_size, void* d_ws, size_t ws_size,
                              hipStream_t stream) {
    const float* features = (const float*)d_in[0];
    const int*   adj      = (const int*)d_in[1];   // integer inputs staged as int32
    const int*   batch1   = (const int*)d_in[2];
    const int*   cols1    = (const int*)d_in[3];
    const int*   cols2    = (const int*)d_in[4];
    const float* ws0      = (const float*)d_in[5];
    const float* wn0      = (const float*)d_in[6];
    const float* ws1      = (const float*)d_in[7];
    const float* wn1      = (const float*)d_in[8];
    float* out = (float*)d_out;

    ushort* wpack = (ushort*)d_ws;                 // 98304 bf16 = 196608 B
    if (ws_size < (size_t)196608) return;          // diagnostic guard

    hipLaunchKernelGGL(k_pack, dim3(384), dim3(256), 0, stream, ws0, wn0, ws1, wn1, wpack);
    hipLaunchKernelGGL(k_fused, dim3(BATCH), dim3(512), 0, stream,
                       features, adj, batch1, cols1, cols2, wpack, out);
}